// Round 1
// baseline (61.822 us; speedup 1.0000x reference)
//
#include <hip/hip_runtime.h>

// GLCM layer: quantize to 8 levels, 8 angle shifts, co-occurrence code,
// 5x5 reflect box filter over 64 one-hot channels, 32x32 avg pool.
// Fused: pooled output = weighted histogram over a 36x36 source window.

#define POOLSZ 32
#define PADR   2        // KS/2
#define H      256
#define W      256
#define NLEV   8
#define NCODE  64
#define NANG   8
#define TILE   38       // 32 + 2*PADR + 2*1 (neighbor halo)

__device__ __forceinline__ int reflect_idx(int t) {
    if (t < 0)   return -t;
    if (t > 255) return 510 - t;
    return t;
}

__global__ __launch_bounds__(256) void glcm_kernel(const float* __restrict__ x,
                                                   float* __restrict__ out) {
    // blockIdx.x = ((b*8 + py)*8 + px)*8 + a
    const int bid = blockIdx.x;
    const int a   = bid & 7;
    const int px  = (bid >> 3) & 7;
    const int py  = (bid >> 6) & 7;
    const int b   = bid >> 9;

    __shared__ signed char gl[TILE][TILE];
    __shared__ float wrow[TILE];
    __shared__ float wcol[TILE];
    __shared__ float hist[NCODE];

    const int tid = threadIdx.x;

    if (tid < NCODE) hist[tid] = 0.0f;

    const int row0 = py * POOLSZ - 3;   // tile origin
    const int col0 = px * POOLSZ - 3;

    // Stage quantized tile (global-clamped indices so halo matches reference clamp)
    const float* xb = x + b * (H * W);
    for (int i = tid; i < TILE * TILE; i += 256) {
        int ly = i / TILE, lx = i % TILE;
        int gy = min(max(row0 + ly, 0), H - 1);
        int gx = min(max(col0 + lx, 0), W - 1);
        float v = xb[gy * W + gx];
        // searchsorted(linspace(0,256,9), v, 'left') - 1  ==  ceil(v/32) - 1  (v=0 -> -1)
        gl[ly][lx] = (signed char)((int)ceilf(v * 0.03125f) - 1);
    }

    // 1-D weights: wrow[l] = #{(y,dy): y in pool block, dy in [-2,2], reflect(y+dy)==s_abs}
    if (tid < 2 * TILE) {
        int dim = tid / TILE;           // 0 = row, 1 = col
        int l   = tid % TILE;
        int o   = dim ? col0 : row0;
        int p   = dim ? px : py;
        int lo  = p * POOLSZ, hi = lo + POOLSZ - 1;
        int s_abs = o + l;
        int wgt = 0;
        if (s_abs >= 0 && s_abs <= 255) {
            for (int t = lo - PADR; t <= hi + PADR; ++t) {
                if (reflect_idx(t) == s_abs) {
                    wgt += min(t + PADR, hi) - max(t - PADR, lo) + 1;
                }
            }
        }
        if (dim) wcol[l] = (float)wgt; else wrow[l] = (float)wgt;
    }
    __syncthreads();

    // angle -> (offy, offx): gl2[y][x] = gl1[clamp(y+offy)][clamp(x+offx)]
    const int offy_t[8] = {0, -1, -1, -1, 0, 1, 1, 1};
    const int offx_t[8] = {1,  1,  0, -1, -1, -1, 0, 1};
    const int offy = offy_t[a], offx = offx_t[a];

    for (int i = tid; i < 36 * 36; i += 256) {
        int ly = i / 36 + 1;
        int lx = i % 36 + 1;
        float w = wrow[ly] * wcol[lx];
        if (w == 0.0f) continue;
        int g1 = gl[ly][lx];
        int g2 = gl[ly + offy][lx + offx];
        int code = g1 * NLEV + g2;       // in [-9, 63]; negative => no one-hot match
        if (code >= 0) atomicAdd(&hist[code], w);
    }
    __syncthreads();

    // out[((b*512 + a*64 + k)*8 + py)*8 + px]
    if (tid < NCODE) {
        float* ob = out + ((size_t)(b * (NANG * NCODE) + a * NCODE) * 64) + py * 8 + px;
        ob[(size_t)tid * 64] = hist[tid] * (1.0f / 1024.0f);
    }
}

extern "C" void kernel_launch(void* const* d_in, const int* in_sizes, int n_in,
                              void* d_out, int out_size, void* d_ws, size_t ws_size,
                              hipStream_t stream) {
    const float* x = (const float*)d_in[0];
    float* out = (float*)d_out;
    glcm_kernel<<<dim3(2 * 8 * 8 * 8), dim3(256), 0, stream>>>(x, out);
}

// Round 2
// 61.634 us; speedup vs baseline: 1.0031x; 1.0031x over previous
//
#include <hip/hip_runtime.h>

// GLCM layer: quantize to 8 levels, 8 angle shifts, co-occurrence code,
// 5x5 reflect box filter over 64 one-hot channels, 32x32 avg pool.
// Fused: pooled output = weighted histogram over a 36x36 source window.
//
// R2: per-wave histogram privatization (no cross-wave atomic serialization),
//     staging/weight role split (waves 0-2 stage tile, wave 3 computes weights).

#define POOLSZ 32
#define PADR   2        // KS/2
#define H      256
#define W      256
#define NLEV   8
#define NCODE  64
#define NANG   8
#define TILE   38       // 32 + 2*PADR + 2*1 (neighbor halo)
#define NWAVE  4

__device__ __forceinline__ int reflect_idx(int t) {
    if (t < 0)   return -t;
    if (t > 255) return 510 - t;
    return t;
}

__global__ __launch_bounds__(256) void glcm_kernel(const float* __restrict__ x,
                                                   float* __restrict__ out) {
    // blockIdx.x = ((b*8 + py)*8 + px)*8 + a
    const int bid = blockIdx.x;
    const int a   = bid & 7;
    const int px  = (bid >> 3) & 7;
    const int py  = (bid >> 6) & 7;
    const int b   = bid >> 9;

    __shared__ signed char gl[TILE][TILE];
    __shared__ float wrow[TILE];
    __shared__ float wcol[TILE];
    __shared__ float hist4[NWAVE * NCODE];   // per-wave privatized histograms

    const int tid = threadIdx.x;
    const int wid = tid >> 6;

    hist4[tid] = 0.0f;                       // each thread zeroes its own slot

    const int row0 = py * POOLSZ - 3;        // tile origin (pool block start - halo)
    const int col0 = px * POOLSZ - 3;

    if (wid < 3) {
        // Waves 0-2 (192 threads): stage quantized tile, global-clamped halo.
        const float* xb = x + b * (H * W);
        for (int i = tid; i < TILE * TILE; i += 192) {
            int ly = i / TILE, lx = i % TILE;
            int gy = min(max(row0 + ly, 0), H - 1);
            int gx = min(max(col0 + lx, 0), W - 1);
            float v = xb[gy * W + gx];
            // searchsorted(linspace(0,256,9), v, 'left')-1 == ceil(v/32)-1 (v=0 -> -1)
            gl[ly][lx] = (signed char)((int)ceilf(v * 0.03125f) - 1);
        }
    } else {
        // Wave 3: 1-D box+pool weights.
        // wrow[l] = sum over pool rows t of overlap of [t-2,t+2] with reflect-image == s
        for (int j = tid - 192; j < 2 * TILE; j += 64) {
            int dim = j / TILE;              // 0 = row, 1 = col
            int l   = j % TILE;
            int o   = dim ? col0 : row0;
            int p   = dim ? px : py;
            int lo  = p * POOLSZ, hi = lo + POOLSZ - 1;
            int s_abs = o + l;
            int wgt = 0;
            if (s_abs >= 0 && s_abs <= 255) {
                for (int t = lo - PADR; t <= hi + PADR; ++t) {
                    if (reflect_idx(t) == s_abs) {
                        wgt += min(t + PADR, hi) - max(t - PADR, lo) + 1;
                    }
                }
            }
            if (dim) wcol[l] = (float)wgt; else wrow[l] = (float)wgt;
        }
    }
    __syncthreads();

    // angle -> (offy, offx): gl2[y][x] = gl1[clamp(y+offy)][clamp(x+offx)]
    const int offy_t[8] = {0, -1, -1, -1, 0, 1, 1, 1};
    const int offx_t[8] = {1,  1,  0, -1, -1, -1, 0, 1};
    const int offy = offy_t[a], offx = offx_t[a];

    float* myhist = &hist4[wid * NCODE];
    for (int i = tid; i < 36 * 36; i += 256) {
        int ly = i / 36 + 1;
        int lx = i % 36 + 1;
        float w = wrow[ly] * wcol[lx];
        int g1 = gl[ly][lx];
        int g2 = gl[ly + offy][lx + offx];
        int code = g1 * NLEV + g2;           // in [-9,63]; negative => no one-hot match
        if (w != 0.0f && code >= 0) atomicAdd(&myhist[code], w);
    }
    __syncthreads();

    // out[((b*512 + a*64 + k)*8 + py)*8 + px]
    if (tid < NCODE) {
        float s = hist4[tid] + hist4[NCODE + tid] + hist4[2 * NCODE + tid]
                + hist4[3 * NCODE + tid];
        float* ob = out + ((size_t)(b * (NANG * NCODE) + a * NCODE) * 64) + py * 8 + px;
        ob[(size_t)tid * 64] = s * (1.0f / 1024.0f);
    }
}

extern "C" void kernel_launch(void* const* d_in, const int* in_sizes, int n_in,
                              void* d_out, int out_size, void* d_ws, size_t ws_size,
                              hipStream_t stream) {
    const float* x = (const float*)d_in[0];
    float* out = (float*)d_out;
    glcm_kernel<<<dim3(2 * 8 * 8 * 8), dim3(256), 0, stream>>>(x, out);
}